// Round 1
// baseline (31.808 us; speedup 1.0000x reference)
//
#include <hip/hip_runtime.h>

// ---------------------------------------------------------------------------
// HybridQFCModel: avg_pool(6) -> take first 4 pooled values -> 4-qubit circuit
// (RX enc, 2x [RZ, CNOT chain, RY]) -> <Z_i> -> BatchNorm1d (training stats)
// Only rows 0..5, cols 0..23 of each 28x28 image are ever used.
// ---------------------------------------------------------------------------

__global__ __launch_bounds__(256) void qfc_main(
    const float* __restrict__ x,
    const float* __restrict__ qp,     // [2][4][2]
    float* __restrict__ out,          // [B][4]  (pre-BN values written here)
    float* __restrict__ partials)     // [nblk][8] : sum(o), sum(o^2)
{
    const int b = blockIdx.x * 256 + threadIdx.x;
    const float* px = x + (size_t)b * 784;

    // --- pooled row 0: windows rows 0..5, col groups {0..5,6..11,12..17,18..23}
    float enc[4] = {0.f, 0.f, 0.f, 0.f};
    #pragma unroll
    for (int r = 0; r < 6; ++r) {
        const float4* row = (const float4*)(px + r * 28);
        #pragma unroll
        for (int q = 0; q < 6; ++q) {
            float4 v = row[q];
            const int c0 = q * 4;
            enc[(c0 + 0) / 6] += v.x;
            enc[(c0 + 1) / 6] += v.y;
            enc[(c0 + 2) / 6] += v.z;
            enc[(c0 + 3) / 6] += v.w;
        }
    }

    // --- RX(enc/36) initial product state. amp(idx) = m * (-i)^k
    float ch[4], sh[4];
    #pragma unroll
    for (int w = 0; w < 4; ++w) {
        float h = enc[w] * (0.5f / 36.0f);
        __sincosf(h, &sh[w], &ch[w]);
    }

    // wire w maps to bit (3-w) of idx (wire0 outermost, C order)
    float sr[16], si[16];
    #pragma unroll
    for (int idx = 0; idx < 16; ++idx) {
        float m = 1.f; int k = 0;
        #pragma unroll
        for (int w = 0; w < 4; ++w) {
            if ((idx >> (3 - w)) & 1) { m *= sh[w]; ++k; }
            else                        m *= ch[w];
        }
        switch (k & 3) {  // (-i)^k
            case 0:  sr[idx] =  m;  si[idx] = 0.f; break;
            case 1:  sr[idx] = 0.f; si[idx] = -m;  break;
            case 2:  sr[idx] = -m;  si[idx] = 0.f; break;
            default: sr[idx] = 0.f; si[idx] =  m;  break;
        }
    }

    #pragma unroll
    for (int l = 0; l < 2; ++l) {
        // RZ layer: diag phase exp(-+ i a_w), a = 0.5*qp[l][w][0]
        #pragma unroll
        for (int w = 0; w < 4; ++w) {
            float a = 0.5f * qp[l * 8 + w * 2 + 0];
            float sa, ca; __sincosf(a, &sa, &ca);
            #pragma unroll
            for (int idx = 0; idx < 16; ++idx) {
                float sg = ((idx >> (3 - w)) & 1) ? sa : -sa;
                float r = sr[idx], mm = si[idx];
                sr[idx] = r * ca - mm * sg;
                si[idx] = r * sg + mm * ca;
            }
        }
        // CNOT chain c -> c+1 : swap target bit where control bit == 1
        #pragma unroll
        for (int c = 0; c < 3; ++c) {
            const int t = c + 1;
            #pragma unroll
            for (int idx = 0; idx < 16; ++idx) {
                if ((((idx >> (3 - c)) & 1) == 1) && (((idx >> (3 - t)) & 1) == 0)) {
                    const int j = idx | (1 << (3 - t));
                    float tr = sr[idx]; sr[idx] = sr[j]; sr[j] = tr;
                    float ti = si[idx]; si[idx] = si[j]; si[j] = ti;
                }
            }
        }
        // RY layer: real rotation [[cb,-sb],[sb,cb]], b = 0.5*qp[l][w][1]
        #pragma unroll
        for (int w = 0; w < 4; ++w) {
            float bb = 0.5f * qp[l * 8 + w * 2 + 1];
            float sb, cb; __sincosf(bb, &sb, &cb);
            #pragma unroll
            for (int idx = 0; idx < 16; ++idx) {
                if (((idx >> (3 - w)) & 1) == 0) {
                    const int j = idx | (1 << (3 - w));
                    float r0 = sr[idx], r1 = sr[j];
                    sr[idx] = cb * r0 - sb * r1;
                    sr[j]   = sb * r0 + cb * r1;
                    float i0 = si[idx], i1 = si[j];
                    si[idx] = cb * i0 - sb * i1;
                    si[j]   = sb * i0 + cb * i1;
                }
            }
        }
    }

    // --- <Z_w> from |amp|^2
    float o[4] = {0.f, 0.f, 0.f, 0.f};
    #pragma unroll
    for (int idx = 0; idx < 16; ++idx) {
        float p = sr[idx] * sr[idx] + si[idx] * si[idx];
        #pragma unroll
        for (int w = 0; w < 4; ++w)
            o[w] += ((idx >> (3 - w)) & 1) ? -p : p;
    }

    // pre-BN store (coalesced 16B per thread)
    float4 ov; ov.x = o[0]; ov.y = o[1]; ov.z = o[2]; ov.w = o[3];
    ((float4*)out)[b] = ov;

    // --- deterministic block reduction of {o, o^2}
    float vals[8] = { o[0], o[1], o[2], o[3],
                      o[0]*o[0], o[1]*o[1], o[2]*o[2], o[3]*o[3] };
    #pragma unroll
    for (int q = 0; q < 8; ++q) {
        float v = vals[q];
        #pragma unroll
        for (int off = 32; off > 0; off >>= 1)
            v += __shfl_down(v, off, 64);
        vals[q] = v;
    }
    __shared__ float red[4][8];
    const int lane = threadIdx.x & 63;
    const int wv   = threadIdx.x >> 6;
    if (lane == 0) {
        #pragma unroll
        for (int q = 0; q < 8; ++q) red[wv][q] = vals[q];
    }
    __syncthreads();
    if (threadIdx.x == 0) {
        #pragma unroll
        for (int q = 0; q < 8; ++q)
            partials[(size_t)blockIdx.x * 8 + q] =
                red[0][q] + red[1][q] + red[2][q] + red[3][q];
    }
}

// One wave: reduce nblk partial rows in fixed order (double accum), emit
// per-qubit scale/shift for the affine BN pass.
__global__ __launch_bounds__(64) void qfc_stats(
    const float* __restrict__ partials,
    const float* __restrict__ gamma,
    const float* __restrict__ beta,
    float* __restrict__ stats,        // [8] = {scale0..3, shift0..3}
    int nblk, int B)
{
    const int lane = threadIdx.x;
    double acc[8];
    #pragma unroll
    for (int q = 0; q < 8; ++q) acc[q] = 0.0;
    for (int r = lane; r < nblk; r += 64) {
        #pragma unroll
        for (int q = 0; q < 8; ++q) acc[q] += (double)partials[(size_t)r * 8 + q];
    }
    #pragma unroll
    for (int q = 0; q < 8; ++q) {
        double v = acc[q];
        #pragma unroll
        for (int off = 32; off > 0; off >>= 1)
            v += __shfl_down(v, off, 64);
        acc[q] = v;
    }
    if (lane == 0) {
        const double invB = 1.0 / (double)B;
        #pragma unroll
        for (int w = 0; w < 4; ++w) {
            double mean = acc[w] * invB;
            double var  = acc[4 + w] * invB - mean * mean;
            double scl  = (double)gamma[w] / sqrt(var + 1e-5);
            stats[w]     = (float)scl;
            stats[4 + w] = (float)((double)beta[w] - mean * scl);
        }
    }
}

__global__ __launch_bounds__(256) void qfc_bn(
    float* __restrict__ out, const float* __restrict__ stats)
{
    const int b = blockIdx.x * 256 + threadIdx.x;
    float s0 = stats[0], s1 = stats[1], s2 = stats[2], s3 = stats[3];
    float t0 = stats[4], t1 = stats[5], t2 = stats[6], t3 = stats[7];
    float4 v = ((float4*)out)[b];
    v.x = v.x * s0 + t0;
    v.y = v.y * s1 + t1;
    v.z = v.z * s2 + t2;
    v.w = v.w * s3 + t3;
    ((float4*)out)[b] = v;
}

extern "C" void kernel_launch(void* const* d_in, const int* in_sizes, int n_in,
                              void* d_out, int out_size, void* d_ws, size_t ws_size,
                              hipStream_t stream)
{
    const float* x  = (const float*)d_in[0];   // [B,1,28,28] f32
    const float* qp = (const float*)d_in[1];   // [2,4,2]
    const float* gm = (const float*)d_in[2];   // [4]
    const float* bt = (const float*)d_in[3];   // [4]
    float* out = (float*)d_out;                // [B,4] f32

    const int B    = in_sizes[0] / 784;        // 131072
    const int nblk = B / 256;                  // 512

    float* partials = (float*)d_ws;            // nblk*8 floats = 16 KB
    float* stats    = partials + (size_t)nblk * 8;  // 8 floats

    qfc_main <<<nblk, 256, 0, stream>>>(x, qp, out, partials);
    qfc_stats<<<1,    64,  0, stream>>>(partials, gm, bt, stats, nblk, B);
    qfc_bn   <<<B/256,256, 0, stream>>>(out, stats);
}